// Round 3
// baseline (601.965 us; speedup 1.0000x reference)
//
#include <hip/hip_runtime.h>

// ---------------------------------------------------------------------------
// BertBiAttention, fp16 MFMA path (fp32 accumulate).
//  - ONE convert launch (inputs + all 6 weight transposes merged).
//  - ONE projection launch (both streams): 256x128 block tile, 4 waves,
//    wave tile 128x64 (32 MFMA per barrier, 42.7 FLOP/LDS-byte vs 32),
//    BK=32 single-buffer m97 2-barrier structure, 34.8 KB LDS ->
//    4 blocks/CU, grid 1152 = 1.125 generations, long (K=1024) blocks
//    first (LPT), XOR swizzle (row>>1)&3, XCD m-strip swizzle,
//    2-pass LDS-transpose epilogue.
//  - ONE flash launch (both phases, phase2-first): RT=2 (128 Q-rows/block),
//    Q frags direct global->VGPR, mask prefetch, no-max softmax, row-sum
//    via ones-MFMA, pipelined K/V staging with counted vmcnt(4).
// ---------------------------------------------------------------------------

typedef _Float16 f16;
typedef unsigned int u32;
typedef f16  v8h __attribute__((ext_vector_type(8)));   // 8 fp16 (4 VGPRs)
typedef float v4f __attribute__((ext_vector_type(4)));  // MFMA acc

struct alignas(8) h4 { f16 x, y, z, w; };

#define GLL16(g, l) __builtin_amdgcn_global_load_lds(                          \
    (const __attribute__((address_space(1))) u32*)(g),                         \
    (__attribute__((address_space(3))) u32*)(l), 16, 0, 0)

#define MFMA16 __builtin_amdgcn_mfma_f32_16x16x32_f16

// ---------------------------------------------------------------------------
// Merged converts: blocks [0,5120) = input fp32->fp16; [5120,6656) = weight
// fp32 [K][1024] -> fp16 [1024][K] transpose (6 weights).
__global__ __launch_bounds__(256)
void cvt_all(const float* __restrict__ p1, long n1,
             const float* __restrict__ p2, long n2,
             f16* __restrict__ d1, f16* __restrict__ d2,
             const float* __restrict__ w0, const float* __restrict__ w1,
             const float* __restrict__ w2, const float* __restrict__ w3,
             const float* __restrict__ w4, const float* __restrict__ w5,
             f16* __restrict__ o1, f16* __restrict__ o2)
{
    __shared__ float t[64][65];
    const int bid = blockIdx.x;
    if (bid < 5120) {
        long i = ((long)bid * 256 + threadIdx.x) * 8;
        const float* s; f16* d;
        if (i < n1) { s = p1 + i; d = d1 + i; }
        else        { long j = i - n1; if (j >= n2) return; s = p2 + j; d = d2 + j; }
        float4 a = *(const float4*)s, b = *(const float4*)(s + 4);
        v8h o = {(f16)a.x, (f16)a.y, (f16)a.z, (f16)a.w,
                 (f16)b.x, (f16)b.y, (f16)b.z, (f16)b.w};
        *(v8h*)d = o;
        return;
    }
    const int id = bid - 5120;                 // 0..1535
    const int z = id >> 8;                     // weight 0..5
    const int rem = id & 255;
    const int K = z < 3 ? 1024 : 768;
    const int bk = (rem >> 4) * 64;
    if (bk >= K) return;
    const float* src = z == 0 ? w0 : z == 1 ? w1 : z == 2 ? w2
                     : z == 3 ? w3 : z == 4 ? w4 : w5;
    f16* dst = z < 3 ? o1 + (size_t)z * 1024 * 1024
                     : o2 + (size_t)(z - 3) * 1024 * 768;

    const int bn = (rem & 15) * 64;
    const int r0 = threadIdx.x >> 4, c4 = (threadIdx.x & 15) * 4;
#pragma unroll
    for (int rr = 0; rr < 64; rr += 16) {
        float4 v = *(const float4*)&src[(long)(bk + rr + r0) * 1024 + bn + c4];
        t[rr + r0][c4 + 0] = v.x; t[rr + r0][c4 + 1] = v.y;
        t[rr + r0][c4 + 2] = v.z; t[rr + r0][c4 + 3] = v.w;
    }
    __syncthreads();
#pragma unroll
    for (int rr = 0; rr < 64; rr += 16) {
        const int n = rr + r0;
        h4 o = {(f16)t[c4 + 0][n], (f16)t[c4 + 1][n],
                (f16)t[c4 + 2][n], (f16)t[c4 + 3][n]};
        *(h4*)&dst[(long)(bn + n) * K + bk + c4] = o;
    }
}

// ---------------------------------------------------------------------------
// Merged projection GEMM.  Blocks [0,384) = stream1 (K=1024, 16 m-tiles),
// [384,1152) = stream2 (K=768, 32 m-tiles).  Block tile 256x128, 4 waves
// (wm in {0,1} x wn in {0,1}), wave tile 128x64: 32 MFMA + 12 ds_read_b128
// per K-iter per wave.  BK=32 single buffer, 2 barriers/iter (m97
// structure): sync -> stage -> sync(drain) -> frags+MFMA.  34.8 KB LDS
// (staging 24 KB; epilogue transpose buf 34.8 KB) -> 4 blocks/CU.
__global__ __launch_bounds__(256, 4)
void mm_proj(const f16* __restrict__ A1, const f16* __restrict__ B1,
             const float* __restrict__ bq1, const float* __restrict__ bk1,
             const float* __restrict__ bv1,
             f16* __restrict__ q1o, f16* __restrict__ k1o, f16* __restrict__ v1o,
             const f16* __restrict__ A2, const f16* __restrict__ B2,
             const float* __restrict__ bq2, const float* __restrict__ bk2,
             const float* __restrict__ bv2,
             f16* __restrict__ q2o, f16* __restrict__ k2o, f16* __restrict__ v2o)
{
    __shared__ f16 sh[17408];            // staging: A[256][32] | B[128][32]

    const int gid = blockIdx.x;
    const bool is1 = gid < 384;
    const int id   = is1 ? gid : gid - 384;
    const int K    = is1 ? 1024 : 768;
    const int S    = is1 ? 256 : 512;
    int by, bx;
    if (is1) { by = (id & 7) * 2 + ((id >> 3) & 1); bx = id >> 4; }
    else     { by = (id & 7) * 4 + ((id >> 3) & 3); bx = id >> 5; }
    const int m0 = by << 8, n0 = bx << 7;
    const f16* A  = is1 ? A1 : A2;
    const f16* Bw = is1 ? B1 : B2;

    const int tid = threadIdx.x, lane = tid & 63, w = tid >> 6;
    const int wm = w >> 1, wn = w & 1;
    const int fr = lane & 15, fq = lane >> 4;          // fq in 0..3

    int aoff[8], boff[4];
#pragma unroll
    for (int mi = 0; mi < 8; ++mi) {
        const int ra = wm * 128 + mi * 16 + fr;
        aoff[mi] = ra * 32 + (fq ^ ((ra >> 1) & 3)) * 8;
    }
#pragma unroll
    for (int n = 0; n < 4; ++n) {
        const int rb = wn * 64 + n * 16 + fr;
        boff[n] = rb * 32 + (fq ^ ((rb >> 1) & 3)) * 8;
    }

    auto stage = [&](int k0) {
#pragma unroll
        for (int j = 0; j < 4; ++j) {              // A: 256 rows x 32
            const int c = j * 256 + tid, row = c >> 2;
            const int kl = (c & 3) ^ ((row >> 1) & 3);
            GLL16(A + (long)(m0 + row) * K + k0 + kl * 8, sh + c * 8);
        }
#pragma unroll
        for (int j = 0; j < 2; ++j) {              // B: 128 rows x 32
            const int c = j * 256 + tid, row = c >> 2;
            const int kl = (c & 3) ^ ((row >> 1) & 3);
            GLL16(Bw + (long)(n0 + row) * K + k0 + kl * 8, sh + 8192 + c * 8);
        }
    };

    v4f acc[8][4];
#pragma unroll
    for (int i = 0; i < 8; ++i)
#pragma unroll
        for (int j = 0; j < 4; ++j) acc[i][j] = (v4f){0.f, 0.f, 0.f, 0.f};

    const int NK = K >> 5;
    for (int kt = 0; kt < NK; ++kt) {
        __syncthreads();                 // prev iter's frag reads done
        stage(kt << 5);
        __syncthreads();                 // staging drained (vmcnt0)
        v8h bh[4];
#pragma unroll
        for (int n = 0; n < 4; ++n) bh[n] = *(const v8h*)&sh[8192 + boff[n]];
#pragma unroll
        for (int mi = 0; mi < 8; ++mi) {
            const v8h ah = *(const v8h*)&sh[aoff[mi]];
#pragma unroll
            for (int n = 0; n < 4; ++n)
                acc[mi][n] = MFMA16(ah, bh[n], acc[mi][n], 0, 0, 0);
        }
    }

    // ---- epilogue; C frag layout: col=lane&15, row=quad*4+reg ----
    const int col = fr, quad = lane >> 4;
    const int seg = n0 >> 10, nbase = n0 & 1023;
    f16* buf = sh;                       // QK: [128][136]; V: [64][264]

    if (seg < 2) {
        const float* bias = seg == 0 ? (is1 ? bq1 : bq2) : (is1 ? bk1 : bk2);
        f16* Co = seg == 0 ? (is1 ? q1o : q2o) : (is1 ? k1o : k2o);
        float bl[4];
#pragma unroll
        for (int n = 0; n < 4; ++n) bl[n] = bias[nbase + wn * 64 + n * 16 + col];
#pragma unroll
        for (int pass = 0; pass < 2; ++pass) {     // m-halves (128 rows)
            __syncthreads();
            if (wm == pass) {
#pragma unroll
                for (int mi = 0; mi < 8; ++mi) {
                    const int ml = mi * 16 + quad * 4;      // 0..127
#pragma unroll
                    for (int n = 0; n < 4; ++n) {
                        const int nl = wn * 64 + n * 16 + col;
#pragma unroll
                        for (int i = 0; i < 4; ++i)
                            buf[(ml + i) * 136 + nl] = (f16)(acc[mi][n][i] + bl[n]);
                    }
                }
            }
            __syncthreads();
            const int rr = tid >> 1, cc = (tid & 1) * 64;
            const long gb = (long)(m0 + pass * 128 + rr) * 1024 + nbase + cc;
#pragma unroll
            for (int c = 0; c < 8; ++c)
                *(v8h*)&Co[gb + c * 8] = *(const v8h*)&buf[rr * 136 + cc + c * 8];
        }
    } else {
        const float* bias = is1 ? bv1 : bv2;
        f16* vo = is1 ? v1o : v2o;
        const int bb = m0 / S, s0 = m0 % S;
#pragma unroll
        for (int pass = 0; pass < 2; ++pass) {     // n-halves (64 cols)
            __syncthreads();
            if (wn == pass) {
#pragma unroll
                for (int mi = 0; mi < 8; ++mi) {
                    const int ml = wm * 128 + mi * 16 + quad * 4;   // 0..255
#pragma unroll
                    for (int n = 0; n < 4; ++n) {
                        const int nl = n * 16 + col;                // 0..63
                        const float bvl = bias[nbase + pass * 64 + nl];
                        h4 o = {(f16)(acc[mi][n][0] + bvl),
                                (f16)(acc[mi][n][1] + bvl),
                                (f16)(acc[mi][n][2] + bvl),
                                (f16)(acc[mi][n][3] + bvl)};
                        *(h4*)&buf[nl * 264 + ml] = o;              // buf[n][m]
                    }
                }
            }
            __syncthreads();
            const int nn = tid >> 2, mm = (tid & 3) * 64;
            const long gb = ((long)bb * 1024 + nbase + pass * 64 + nn) * S + s0 + mm;
#pragma unroll
            for (int c = 0; c < 8; ++c)
                *(v8h*)&vo[gb + c * 8] = *(const v8h*)&buf[nn * 264 + mm + c * 8];
        }
    }
}

// ---------------------------------------------------------------------------
// Merged fused flash attention, RT=2 (128 Q-rows/block; wave owns 32 rows).
// Blocks [0,256) = phase2 (q1 vs k2/v2, 8 k-tiles -> launched first);
// [256,768) = phase1 (q2 vs k1/v1, 4 k-tiles).
// Pipelined staging, single K and V buffers (counted vmcnt, never 0
// mid-loop); Q frags direct global->VGPR; no-max softmax; l via ones-MFMA.
__global__ __launch_bounds__(256, 2)
void flash(const f16* __restrict__ q2, const f16* __restrict__ k1,
           const f16* __restrict__ v1, const float* __restrict__ m1,
           float* __restrict__ o1,
           const f16* __restrict__ q1, const f16* __restrict__ k2,
           const f16* __restrict__ v2, const float* __restrict__ m2,
           float* __restrict__ o2, float scale)
{
    constexpr int PSTR = 72;                    // 144 B rows: b128-aligned
    __shared__ f16 lds[16384 + 128 * PSTR];     // 51.2 KB
    f16* KL = lds;                              // [64][128] swizzled
    f16* VL = lds + 8192;                       // [128][64] swizzled
    f16* PL = lds + 16384;                      // [128][72]

    const int gid = blockIdx.x;
    const bool ph2 = gid < 256;
    const int id = ph2 ? gid : gid - 256;
    const int Sq = ph2 ? 256 : 512, Sk = ph2 ? 512 : 256;
    const f16* qp = ph2 ? q1 : q2;
    const f16* kp = ph2 ? k2 : k1;
    const f16* vp = ph2 ? v2 : v1;
    const float* mask = ph2 ? m2 : m1;
    float* out = ph2 ? o2 : o1;

    const int zz = id & 127, yy = id >> 7;
    const int b = zz >> 3, hd = zz & 7;
    const int q0 = yy * 128;
    const int tid = threadIdx.x, lane = tid & 63, w = tid >> 6;
    const int col = lane & 15, quad = lane >> 4;

    // ---- Q fragments: direct global -> VGPR (row = q0 + w*32 + rt*16 + col)
    v8h qf[2][4];
#pragma unroll
    for (int rt = 0; rt < 2; ++rt) {
        const long qr = ((long)b * Sq + q0 + w * 32 + rt * 16 + col) * 1024
                        + (long)hd * 128;
#pragma unroll
        for (int kf = 0; kf < 4; ++kf)
            qf[rt][kf] = *(const v8h*)(qp + qr + kf * 32 + quad * 8);
    }

    v8h ones;
#pragma unroll
    for (int i = 0; i < 8; ++i) ones[i] = (f16)1.0f;

    v4f O[2][8], Lc[2];
#pragma unroll
    for (int rt = 0; rt < 2; ++rt) {
#pragma unroll
        for (int nj = 0; nj < 8; ++nj) O[rt][nj] = (v4f){0.f, 0.f, 0.f, 0.f};
        Lc[rt] = (v4f){0.f, 0.f, 0.f, 0.f};
    }

    const long kbase = (long)b * Sk * 1024 + (long)hd * 128;
    const long vbase = ((long)b * 1024 + hd * 128) * (long)Sk;
    const int nk = Sk >> 6;

    auto stageK = [&](int kt) {                 // K tile 64x128, 4 GLL16
#pragma unroll
        for (int j = 0; j < 4; ++j) {
            const int c = j * 256 + tid, row = c >> 4, ch = (c & 15) ^ (row & 15);
            GLL16(kp + kbase + (long)(kt * 64 + row) * 1024 + ch * 8, KL + c * 8);
        }
    };
    auto stageV = [&](int kt) {                 // V tile 128x64 (transposed src)
#pragma unroll
        for (int j = 0; j < 4; ++j) {
            const int c = j * 256 + tid, row = c >> 3, ch = (c & 7) ^ (row & 7);
            GLL16(vp + vbase + (long)row * Sk + kt * 64 + ch * 8, VL + c * 8);
        }
    };

    stageK(0);                                  // per-thread issue order: K, V
    stageV(0);

    float mv[4];
#pragma unroll
    for (int tn = 0; tn < 4; ++tn)
        mv[tn] = mask[(long)b * Sk + tn * 16 + col];

    for (int kt = 0; kt < nk; ++kt) {
        // ---- entry: K(kt) landed (oldest 4 of <=8 outstanding) ----
        asm volatile("s_waitcnt vmcnt(4)" ::: "memory");
        __builtin_amdgcn_sched_barrier(0);
        __builtin_amdgcn_s_barrier();

        // ---- S = Q K^T (both rt share each bh load) ----
        v4f sa[2][4];
#pragma unroll
        for (int rt = 0; rt < 2; ++rt)
#pragma unroll
            for (int tn = 0; tn < 4; ++tn) sa[rt][tn] = (v4f){0.f, 0.f, 0.f, 0.f};
#pragma unroll
        for (int kf = 0; kf < 4; ++kf) {
            v8h bh[4];
#pragma unroll
            for (int tn = 0; tn < 4; ++tn) {
                const int row = tn * 16 + col;
                bh[tn] = *(const v8h*)&KL[row * 128 + ((kf * 4 + quad) ^ (row & 15)) * 8];
            }
            __builtin_amdgcn_s_setprio(1);
#pragma unroll
            for (int rt = 0; rt < 2; ++rt)
#pragma unroll
                for (int tn = 0; tn < 4; ++tn)
                    sa[rt][tn] = MFMA16(qf[rt][kf], bh[tn], sa[rt][tn], 0, 0, 0);
            __builtin_amdgcn_s_setprio(0);
        }

        // prefetch next tile's mask
        float mvn[4];
        if (kt + 1 < nk) {
#pragma unroll
            for (int tn = 0; tn < 4; ++tn)
                mvn[tn] = mask[(long)b * Sk + (kt + 1) * 64 + tn * 16 + col];
        }

        // ---- all KL reads done -> re-stage K(kt+1) into same buffer ----
        asm volatile("s_waitcnt lgkmcnt(0)" ::: "memory");
        __builtin_amdgcn_sched_barrier(0);
        __builtin_amdgcn_s_barrier();
        if (kt + 1 < nk) stageK(kt + 1);

        // ---- p = exp(s*scale + mask) -> PL (C-layout -> A-layout) ----
#pragma unroll
        for (int rt = 0; rt < 2; ++rt)
#pragma unroll
            for (int tn = 0; tn < 4; ++tn)
#pragma unroll
                for (int r = 0; r < 4; ++r) {
                    const float p = __expf(sa[rt][tn][r] * scale + mv[tn]);
                    PL[(w * 32 + rt * 16 + quad * 4 + r) * PSTR + tn * 16 + col]
                        = (f16)p;
                }

        // ---- V(kt) landed (oldest 4: V(kt); K(kt+1) may stay in flight) ----
        if (kt + 1 < nk) asm volatile("s_waitcnt vmcnt(4)" ::: "memory");
        else             asm volatile("s_waitcnt vmcnt(0)" ::: "memory");
        __builtin_amdgcn_sched_barrier(0);
        __builtin_amdgcn_s_barrier();

        // ---- O += P @ V, l += P @ ones ----
#pragma unroll
        for (int kf2 = 0; kf2 < 2; ++kf2) {
            v8h vb[8];
#pragma unroll
            for (int nj = 0; nj < 8; ++nj) {
                const int row = nj * 16 + col;
                vb[nj] = *(const v8h*)&VL[row * 64 + ((kf2 * 4 + quad) ^ (row & 7)) * 8];
            }
#pragma unroll
            for (int rt = 0; rt < 2; ++rt) {
                const v8h pa = *(const v8h*)&PL[(w * 32 + rt * 16 + col) * PSTR
                                                + kf2 * 32 + quad * 8];
                __builtin_amdgcn_s_setprio(1);
#pragma unroll
                for (int nj = 0; nj < 8; ++nj)
                    O[rt][nj] = MFMA16(pa, vb[nj], O[rt][nj], 0, 0, 0);
                Lc[rt] = MFMA16(pa, ones, Lc[rt], 0, 0, 0);
                __builtin_amdgcn_s_setprio(0);
            }
        }

        // ---- all VL reads done -> re-stage V(kt+1) ----
        asm volatile("s_waitcnt lgkmcnt(0)" ::: "memory");
        __builtin_amdgcn_sched_barrier(0);
        __builtin_amdgcn_s_barrier();
        if (kt + 1 < nk) stageV(kt + 1);

#pragma unroll
        for (int tn = 0; tn < 4; ++tn) mv[tn] = mvn[tn];
    }

    // ---- epilogue: O /= l ----
#pragma unroll
    for (int rt = 0; rt < 2; ++rt) {
        float inv[4];
#pragma unroll
        for (int r = 0; r < 4; ++r) inv[r] = 1.0f / Lc[rt][r];
        const long ob = ((long)b * Sq + q0 + w * 32 + rt * 16 + quad * 4) * 1024
                        + (long)hd * 128;
#pragma unroll
        for (int nj = 0; nj < 8; ++nj)
#pragma unroll
            for (int r = 0; r < 4; ++r)
                out[ob + (long)r * 1024 + nj * 16 + col] = O[rt][nj][r] * inv[r];
    }
}

// ---------------------------------------------------------------------------
extern "C" void kernel_launch(void* const* d_in, const int* in_sizes, int n_in,
                              void* d_out, int out_size, void* d_ws, size_t ws_size,
                              hipStream_t stream)
{
    const float* in1   = (const float*)d_in[0];
    const float* mask1 = (const float*)d_in[1];
    const float* in2   = (const float*)d_in[2];
    const float* mask2 = (const float*)d_in[3];
    const float* Wq1 = (const float*)d_in[4];  const float* bq1 = (const float*)d_in[5];
    const float* Wk1 = (const float*)d_in[6];  const float* bk1 = (const float*)d_in[7];
    const float* Wv1 = (const float*)d_in[8];  const float* bv1 = (const float*)d_in[9];
    const float* Wq2 = (const float*)d_in[10]; const float* bq2 = (const float*)d_in[11];
    const float* Wk2 = (const float*)d_in[12]; const float* bk2 = (const float*)d_in[13];
    const float* Wv2 = (const float*)d_in[14]; const float* bv2 = (const float*)d_in[15];

    constexpr int Bb = 16, S1 = 256, S2 = 512, VH = 1024, TH = 768;
    constexpr long M1 = (long)Bb * S1, M2 = (long)Bb * S2;
    const float scale = 0.088388347648318447f;   // 1/sqrt(128)

    // ---- workspace (fp16 elements) ----
    f16* W = (f16*)d_ws;
    f16* i1  = W;                        // [4096][1024]
    f16* i2  = i1 + M1 * VH;             // [8192][768]
    f16* w1  = i2 + M2 * TH;             // [3072][1024]
    f16* w2  = w1 + (long)3072 * VH;     // [3072][768]
    f16* q1  = w2 + (long)3072 * TH;     // [4096][1024]
    f16* k1  = q1 + M1 * 1024;
    f16* v1t = k1 + M1 * 1024;           // [16][1024][256]
    f16* q2  = v1t + M1 * 1024;          // [8192][1024]
    f16* k2  = q2 + M2 * 1024;
    f16* v2t = k2 + M2 * 1024;           // [16][1024][512]
    float* out = (float*)d_out;

    // ---- merged converts: 5120 input blocks + 1536 weight blocks ----
    cvt_all<<<dim3(6656), 256, 0, stream>>>(
        in1, M1 * VH, in2, M2 * TH, i1, i2,
        Wq1, Wk1, Wv1, Wq2, Wk2, Wv2, w1, w2);

    // ---- merged projections: 384 (s1, K=1024, long first) + 768 (s2) ----
    mm_proj<<<dim3(1152), 256, 0, stream>>>(
        i1, w1, bq1, bk1, bv1, q1, k1, v1t,
        i2, w2, bq2, bk2, bv2, q2, k2, v2t);

    // ---- merged fused attention: 256 (phase2, long) + 512 (phase1) ----
    flash<<<dim3(768), 256, 0, stream>>>(
        q2, k1, v1t, mask1, out,
        q1, k2, v2t, mask2, out + M2 * 1024, scale);
}

// Round 4
// 251.594 us; speedup vs baseline: 2.3926x; 2.3926x over previous
//
#include <hip/hip_runtime.h>

// ---------------------------------------------------------------------------
// BertBiAttention, fp16 MFMA path (fp32 accumulate).
//  - ONE convert launch (inputs + all 6 weight transposes merged).
//  - ONE projection launch (both streams): 256x128 block tile, 512 threads
//    (8 waves of 64x64 -> acc[4][4]: 64 VGPR + 64 AGPR, fits the
//    launch_bounds(512,4) cap of 128 combined -- R3 lesson: acc[8][4]
//    spilled to scratch, 1 GB of writes).  BK=32 LDS DOUBLE-buffer,
//    R0's verified 2-barrier loop, XOR swizzle (row>>1)&3, XCD m-strips,
//    long-K blocks first, 2-pass LDS-transpose epilogue.
//  - ONE flash launch (both phases, phase2-first): RT=2 (128 Q-rows/block),
//    Q frags direct global->VGPR, mask prefetch, no-max softmax, row-sum
//    via ones-MFMA, pipelined K/V staging with counted vmcnt(4).
// ---------------------------------------------------------------------------

typedef _Float16 f16;
typedef unsigned int u32;
typedef f16  v8h __attribute__((ext_vector_type(8)));   // 8 fp16 (4 VGPRs)
typedef float v4f __attribute__((ext_vector_type(4)));  // MFMA acc

struct alignas(8) h4 { f16 x, y, z, w; };

#define GLL16(g, l) __builtin_amdgcn_global_load_lds(                          \
    (const __attribute__((address_space(1))) u32*)(g),                         \
    (__attribute__((address_space(3))) u32*)(l), 16, 0, 0)

#define MFMA16 __builtin_amdgcn_mfma_f32_16x16x32_f16

// ---------------------------------------------------------------------------
// Merged converts: blocks [0,5120) = input fp32->fp16; [5120,6656) = weight
// fp32 [K][1024] -> fp16 [1024][K] transpose (6 weights).
__global__ __launch_bounds__(256)
void cvt_all(const float* __restrict__ p1, long n1,
             const float* __restrict__ p2, long n2,
             f16* __restrict__ d1, f16* __restrict__ d2,
             const float* __restrict__ w0, const float* __restrict__ w1,
             const float* __restrict__ w2, const float* __restrict__ w3,
             const float* __restrict__ w4, const float* __restrict__ w5,
             f16* __restrict__ o1, f16* __restrict__ o2)
{
    __shared__ float t[64][65];
    const int bid = blockIdx.x;
    if (bid < 5120) {
        long i = ((long)bid * 256 + threadIdx.x) * 8;
        const float* s; f16* d;
        if (i < n1) { s = p1 + i; d = d1 + i; }
        else        { long j = i - n1; if (j >= n2) return; s = p2 + j; d = d2 + j; }
        float4 a = *(const float4*)s, b = *(const float4*)(s + 4);
        v8h o = {(f16)a.x, (f16)a.y, (f16)a.z, (f16)a.w,
                 (f16)b.x, (f16)b.y, (f16)b.z, (f16)b.w};
        *(v8h*)d = o;
        return;
    }
    const int id = bid - 5120;                 // 0..1535
    const int z = id >> 8;                     // weight 0..5
    const int rem = id & 255;
    const int K = z < 3 ? 1024 : 768;
    const int bk = (rem >> 4) * 64;
    if (bk >= K) return;
    const float* src = z == 0 ? w0 : z == 1 ? w1 : z == 2 ? w2
                     : z == 3 ? w3 : z == 4 ? w4 : w5;
    f16* dst = z < 3 ? o1 + (size_t)z * 1024 * 1024
                     : o2 + (size_t)(z - 3) * 1024 * 768;

    const int bn = (rem & 15) * 64;
    const int r0 = threadIdx.x >> 4, c4 = (threadIdx.x & 15) * 4;
#pragma unroll
    for (int rr = 0; rr < 64; rr += 16) {
        float4 v = *(const float4*)&src[(long)(bk + rr + r0) * 1024 + bn + c4];
        t[rr + r0][c4 + 0] = v.x; t[rr + r0][c4 + 1] = v.y;
        t[rr + r0][c4 + 2] = v.z; t[rr + r0][c4 + 3] = v.w;
    }
    __syncthreads();
#pragma unroll
    for (int rr = 0; rr < 64; rr += 16) {
        const int n = rr + r0;
        h4 o = {(f16)t[c4 + 0][n], (f16)t[c4 + 1][n],
                (f16)t[c4 + 2][n], (f16)t[c4 + 3][n]};
        *(h4*)&dst[(long)(bn + n) * K + bk + c4] = o;
    }
}

// ---------------------------------------------------------------------------
// Merged projection GEMM.  Blocks [0,384) = stream1 (K=1024, 16 m-tiles),
// [384,1152) = stream2 (K=768, 32 m-tiles).  Block tile 256x128, 8 waves
// (wm=w>>1 in 0..3, wn=w&1), wave tile 64x64 -> acc[4][4] (64 AGPR) +
// 8 v8h frags (32 VGPR): fits 128-combined cap, NO SPILL.  BK=32 double
// buffer (2 x 24 KB), one barrier-pair per K-iter (verified R0 loop).
// LDS 48 KB -> 2 blocks/CU (VGPR-capped anyway), 16 waves/CU.
__global__ __launch_bounds__(512, 4)
void mm_proj(const f16* __restrict__ A1, const f16* __restrict__ B1,
             const float* __restrict__ bq1, const float* __restrict__ bk1,
             const float* __restrict__ bv1,
             f16* __restrict__ q1o, f16* __restrict__ k1o, f16* __restrict__ v1o,
             const f16* __restrict__ A2, const f16* __restrict__ B2,
             const float* __restrict__ bq2, const float* __restrict__ bk2,
             const float* __restrict__ bv2,
             f16* __restrict__ q2o, f16* __restrict__ k2o, f16* __restrict__ v2o)
{
    __shared__ f16 sh[24576];            // dbuf: {A[256][32] B[128][32]} x 2

    const int gid = blockIdx.x;
    const bool is1 = gid < 384;
    const int id   = is1 ? gid : gid - 384;
    const int K    = is1 ? 1024 : 768;
    const int S    = is1 ? 256 : 512;
    int by, bx;
    if (is1) { by = (id & 7) * 2 + ((id >> 3) & 1); bx = id >> 4; }
    else     { by = (id & 7) * 4 + ((id >> 3) & 3); bx = id >> 5; }
    const int m0 = by << 8, n0 = bx << 7;
    const f16* A  = is1 ? A1 : A2;
    const f16* Bw = is1 ? B1 : B2;

    const int tid = threadIdx.x, lane = tid & 63, w = tid >> 6;
    const int wm = w >> 1, wn = w & 1;                 // 4 x 2 waves of 64x64
    const int fr = lane & 15, fq = lane >> 4;          // fq in 0..3

    int aoff[4], boff[4];
#pragma unroll
    for (int t = 0; t < 4; ++t) {
        const int ra = wm * 64 + t * 16 + fr;          // A row 0..255
        aoff[t] = ra * 32 + (fq ^ ((ra >> 1) & 3)) * 8;
        const int rb = wn * 64 + t * 16 + fr;          // B row 0..127
        boff[t] = rb * 32 + (fq ^ ((rb >> 1) & 3)) * 8;
    }

    auto stage = [&](int k0, int p) {
        f16* Ad = sh + p * 12288;
        f16* Bd = sh + p * 12288 + 8192;
#pragma unroll
        for (int j = 0; j < 2; ++j) {              // A: 256 rows x 32
            const int c = j * 512 + tid, row = c >> 2;
            const int kl = (c & 3) ^ ((row >> 1) & 3);
            GLL16(A + (long)(m0 + row) * K + k0 + kl * 8, Ad + c * 8);
        }
        {                                          // B: 128 rows x 32
            const int c = tid, row = c >> 2;
            const int kl = (c & 3) ^ ((row >> 1) & 3);
            GLL16(Bw + (long)(n0 + row) * K + k0 + kl * 8, Bd + c * 8);
        }
    };

    v4f acc[4][4];
#pragma unroll
    for (int i = 0; i < 4; ++i)
#pragma unroll
        for (int j = 0; j < 4; ++j) acc[i][j] = (v4f){0.f, 0.f, 0.f, 0.f};

    stage(0, 0);
    const int NK = K >> 5;
    for (int kt = 0; kt < NK; ++kt) {
        __syncthreads();                 // drains GLL(kt); prev compute done
        if (kt + 1 < NK) stage((kt + 1) << 5, (kt + 1) & 1);
        const f16* As = sh + (kt & 1) * 12288;
        const f16* Bs = As + 8192;
        v8h ah[4], bh[4];
#pragma unroll
        for (int t = 0; t < 4; ++t) ah[t] = *(const v8h*)&As[aoff[t]];
#pragma unroll
        for (int t = 0; t < 4; ++t) bh[t] = *(const v8h*)&Bs[boff[t]];
#pragma unroll
        for (int tmi = 0; tmi < 4; ++tmi)
#pragma unroll
            for (int tni = 0; tni < 4; ++tni)
                acc[tmi][tni] = MFMA16(ah[tmi], bh[tni], acc[tmi][tni], 0, 0, 0);
    }

    // ---- epilogue; C frag layout: col=lane&15, row=quad*4+reg ----
    const int col = fr, quad = lane >> 4;
    const int seg = n0 >> 10, nbase = n0 & 1023;
    f16* buf = sh;                       // QK: [128][136]=17408; V: [64][264]=16896

    if (seg < 2) {
        const float* bias = seg == 0 ? (is1 ? bq1 : bq2) : (is1 ? bk1 : bk2);
        f16* Co = seg == 0 ? (is1 ? q1o : q2o) : (is1 ? k1o : k2o);
        float bl[4];
#pragma unroll
        for (int n = 0; n < 4; ++n) bl[n] = bias[nbase + wn * 64 + n * 16 + col];
#pragma unroll
        for (int pass = 0; pass < 2; ++pass) {     // m-halves (128 rows)
            __syncthreads();
            if ((wm >> 1) == pass) {
#pragma unroll
                for (int tmi = 0; tmi < 4; ++tmi) {
                    const int ml = (wm & 1) * 64 + tmi * 16 + quad * 4;  // 0..127
#pragma unroll
                    for (int n = 0; n < 4; ++n) {
                        const int nl = wn * 64 + n * 16 + col;
#pragma unroll
                        for (int i = 0; i < 4; ++i)
                            buf[(ml + i) * 136 + nl] = (f16)(acc[tmi][n][i] + bl[n]);
                    }
                }
            }
            __syncthreads();
            const int rr = tid >> 2, cc = (tid & 3) * 32;
            const long gb = (long)(m0 + pass * 128 + rr) * 1024 + nbase + cc;
#pragma unroll
            for (int c = 0; c < 4; ++c)
                *(v8h*)&Co[gb + c * 8] = *(const v8h*)&buf[rr * 136 + cc + c * 8];
        }
    } else {
        const float* bias = is1 ? bv1 : bv2;
        f16* vo = is1 ? v1o : v2o;
        const int bb = m0 / S, s0 = m0 % S;
        float bl[4];
#pragma unroll
        for (int n = 0; n < 4; ++n) bl[n] = bias[nbase + wn * 64 + n * 16 + col];
#pragma unroll
        for (int pass = 0; pass < 2; ++pass) {     // n-halves (64 cols)
            __syncthreads();
            if (wn == pass) {
#pragma unroll
                for (int tmi = 0; tmi < 4; ++tmi) {
                    const int ml = wm * 64 + tmi * 16 + quad * 4;    // 0..255
#pragma unroll
                    for (int n = 0; n < 4; ++n) {
                        const int nl = n * 16 + col;                 // 0..63
                        h4 o = {(f16)(acc[tmi][n][0] + bl[n]),
                                (f16)(acc[tmi][n][1] + bl[n]),
                                (f16)(acc[tmi][n][2] + bl[n]),
                                (f16)(acc[tmi][n][3] + bl[n])};
                        *(h4*)&buf[nl * 264 + ml] = o;               // buf[n][m]
                    }
                }
            }
            __syncthreads();
            const int nn = tid >> 3, mm = (tid & 7) * 32;
            const long gb = ((long)bb * 1024 + nbase + pass * 64 + nn) * S + s0 + mm;
#pragma unroll
            for (int c = 0; c < 4; ++c)
                *(v8h*)&vo[gb + c * 8] = *(const v8h*)&buf[nn * 264 + mm + c * 8];
        }
    }
}

// ---------------------------------------------------------------------------
// Merged fused flash attention, RT=2 (128 Q-rows/block; wave owns 32 rows).
// Blocks [0,256) = phase2 (q1 vs k2/v2, 8 k-tiles -> launched first);
// [256,768) = phase1 (q2 vs k1/v1, 4 k-tiles).
// Pipelined staging, single K and V buffers (counted vmcnt, never 0
// mid-loop); Q frags direct global->VGPR; no-max softmax; l via ones-MFMA.
__global__ __launch_bounds__(256, 2)
void flash(const f16* __restrict__ q2, const f16* __restrict__ k1,
           const f16* __restrict__ v1, const float* __restrict__ m1,
           float* __restrict__ o1,
           const f16* __restrict__ q1, const f16* __restrict__ k2,
           const f16* __restrict__ v2, const float* __restrict__ m2,
           float* __restrict__ o2, float scale)
{
    constexpr int PSTR = 72;                    // 144 B rows: b128-aligned
    __shared__ f16 lds[16384 + 128 * PSTR];     // 51.2 KB
    f16* KL = lds;                              // [64][128] swizzled
    f16* VL = lds + 8192;                       // [128][64] swizzled
    f16* PL = lds + 16384;                      // [128][72]

    const int gid = blockIdx.x;
    const bool ph2 = gid < 256;
    const int id = ph2 ? gid : gid - 256;
    const int Sq = ph2 ? 256 : 512, Sk = ph2 ? 512 : 256;
    const f16* qp = ph2 ? q1 : q2;
    const f16* kp = ph2 ? k2 : k1;
    const f16* vp = ph2 ? v2 : v1;
    const float* mask = ph2 ? m2 : m1;
    float* out = ph2 ? o2 : o1;

    const int zz = id & 127, yy = id >> 7;
    const int b = zz >> 3, hd = zz & 7;
    const int q0 = yy * 128;
    const int tid = threadIdx.x, lane = tid & 63, w = tid >> 6;
    const int col = lane & 15, quad = lane >> 4;

    // ---- Q fragments: direct global -> VGPR (row = q0 + w*32 + rt*16 + col)
    v8h qf[2][4];
#pragma unroll
    for (int rt = 0; rt < 2; ++rt) {
        const long qr = ((long)b * Sq + q0 + w * 32 + rt * 16 + col) * 1024
                        + (long)hd * 128;
#pragma unroll
        for (int kf = 0; kf < 4; ++kf)
            qf[rt][kf] = *(const v8h*)(qp + qr + kf * 32 + quad * 8);
    }

    v8h ones;
#pragma unroll
    for (int i = 0; i < 8; ++i) ones[i] = (f16)1.0f;

    v4f O[2][8], Lc[2];
#pragma unroll
    for (int rt = 0; rt < 2; ++rt) {
#pragma unroll
        for (int nj = 0; nj < 8; ++nj) O[rt][nj] = (v4f){0.f, 0.f, 0.f, 0.f};
        Lc[rt] = (v4f){0.f, 0.f, 0.f, 0.f};
    }

    const long kbase = (long)b * Sk * 1024 + (long)hd * 128;
    const long vbase = ((long)b * 1024 + hd * 128) * (long)Sk;
    const int nk = Sk >> 6;

    auto stageK = [&](int kt) {                 // K tile 64x128, 4 GLL16
#pragma unroll
        for (int j = 0; j < 4; ++j) {
            const int c = j * 256 + tid, row = c >> 4, ch = (c & 15) ^ (row & 15);
            GLL16(kp + kbase + (long)(kt * 64 + row) * 1024 + ch * 8, KL + c * 8);
        }
    };
    auto stageV = [&](int kt) {                 // V tile 128x64 (transposed src)
#pragma unroll
        for (int j = 0; j < 4; ++j) {
            const int c = j * 256 + tid, row = c >> 3, ch = (c & 7) ^ (row & 7);
            GLL16(vp + vbase + (long)row * Sk + kt * 64 + ch * 8, VL + c * 8);
        }
    };

    stageK(0);                                  // per-thread issue order: K, V
    stageV(0);

    float mv[4];
#pragma unroll
    for (int tn = 0; tn < 4; ++tn)
        mv[tn] = mask[(long)b * Sk + tn * 16 + col];

    for (int kt = 0; kt < nk; ++kt) {
        // ---- entry: K(kt) landed (oldest 4 of <=8 outstanding) ----
        asm volatile("s_waitcnt vmcnt(4)" ::: "memory");
        __builtin_amdgcn_sched_barrier(0);
        __builtin_amdgcn_s_barrier();

        // ---- S = Q K^T (both rt share each bh load) ----
        v4f sa[2][4];
#pragma unroll
        for (int rt = 0; rt < 2; ++rt)
#pragma unroll
            for (int tn = 0; tn < 4; ++tn) sa[rt][tn] = (v4f){0.f, 0.f, 0.f, 0.f};
#pragma unroll
        for (int kf = 0; kf < 4; ++kf) {
            v8h bh[4];
#pragma unroll
            for (int tn = 0; tn < 4; ++tn) {
                const int row = tn * 16 + col;
                bh[tn] = *(const v8h*)&KL[row * 128 + ((kf * 4 + quad) ^ (row & 15)) * 8];
            }
            __builtin_amdgcn_s_setprio(1);
#pragma unroll
            for (int rt = 0; rt < 2; ++rt)
#pragma unroll
                for (int tn = 0; tn < 4; ++tn)
                    sa[rt][tn] = MFMA16(qf[rt][kf], bh[tn], sa[rt][tn], 0, 0, 0);
            __builtin_amdgcn_s_setprio(0);
        }

        // prefetch next tile's mask
        float mvn[4];
        if (kt + 1 < nk) {
#pragma unroll
            for (int tn = 0; tn < 4; ++tn)
                mvn[tn] = mask[(long)b * Sk + (kt + 1) * 64 + tn * 16 + col];
        }

        // ---- all KL reads done -> re-stage K(kt+1) into same buffer ----
        asm volatile("s_waitcnt lgkmcnt(0)" ::: "memory");
        __builtin_amdgcn_sched_barrier(0);
        __builtin_amdgcn_s_barrier();
        if (kt + 1 < nk) stageK(kt + 1);

        // ---- p = exp(s*scale + mask) -> PL (C-layout -> A-layout) ----
#pragma unroll
        for (int rt = 0; rt < 2; ++rt)
#pragma unroll
            for (int tn = 0; tn < 4; ++tn)
#pragma unroll
                for (int r = 0; r < 4; ++r) {
                    const float p = __expf(sa[rt][tn][r] * scale + mv[tn]);
                    PL[(w * 32 + rt * 16 + quad * 4 + r) * PSTR + tn * 16 + col]
                        = (f16)p;
                }

        // ---- V(kt) landed (oldest 4: V(kt); K(kt+1) may stay in flight) ----
        if (kt + 1 < nk) asm volatile("s_waitcnt vmcnt(4)" ::: "memory");
        else             asm volatile("s_waitcnt vmcnt(0)" ::: "memory");
        __builtin_amdgcn_sched_barrier(0);
        __builtin_amdgcn_s_barrier();

        // ---- O += P @ V, l += P @ ones ----
#pragma unroll
        for (int kf2 = 0; kf2 < 2; ++kf2) {
            v8h vb[8];
#pragma unroll
            for (int nj = 0; nj < 8; ++nj) {
                const int row = nj * 16 + col;
                vb[nj] = *(const v8h*)&VL[row * 64 + ((kf2 * 4 + quad) ^ (row & 7)) * 8];
            }
#pragma unroll
            for (int rt = 0; rt < 2; ++rt) {
                const v8h pa = *(const v8h*)&PL[(w * 32 + rt * 16 + col) * PSTR
                                                + kf2 * 32 + quad * 8];
                __builtin_amdgcn_s_setprio(1);
#pragma unroll
                for (int nj = 0; nj < 8; ++nj)
                    O[rt][nj] = MFMA16(pa, vb[nj], O[rt][nj], 0, 0, 0);
                Lc[rt] = MFMA16(pa, ones, Lc[rt], 0, 0, 0);
                __builtin_amdgcn_s_setprio(0);
            }
        }

        // ---- all VL reads done -> re-stage V(kt+1) ----
        asm volatile("s_waitcnt lgkmcnt(0)" ::: "memory");
        __builtin_amdgcn_sched_barrier(0);
        __builtin_amdgcn_s_barrier();
        if (kt + 1 < nk) stageV(kt + 1);

#pragma unroll
        for (int tn = 0; tn < 4; ++tn) mv[tn] = mvn[tn];
    }

    // ---- epilogue: O /= l ----
#pragma unroll
    for (int rt = 0; rt < 2; ++rt) {
        float inv[4];
#pragma unroll
        for (int r = 0; r < 4; ++r) inv[r] = 1.0f / Lc[rt][r];
        const long ob = ((long)b * Sq + q0 + w * 32 + rt * 16 + quad * 4) * 1024
                        + (long)hd * 128;
#pragma unroll
        for (int nj = 0; nj < 8; ++nj)
#pragma unroll
            for (int r = 0; r < 4; ++r)
                out[ob + (long)r * 1024 + nj * 16 + col] = O[rt][nj][r] * inv[r];
    }
}

// ---------------------------------------------------------------------------
extern "C" void kernel_launch(void* const* d_in, const int* in_sizes, int n_in,
                              void* d_out, int out_size, void* d_ws, size_t ws_size,
                              hipStream_t stream)
{
    const float* in1   = (const float*)d_in[0];
    const float* mask1 = (const float*)d_in[1];
    const float* in2   = (const float*)d_in[2];
    const float* mask2 = (const float*)d_in[3];
    const float* Wq1 = (const float*)d_in[4];  const float* bq1 = (const float*)d_in[5];
    const float* Wk1 = (const float*)d_in[6];  const float* bk1 = (const float*)d_in[7];
    const float* Wv1 = (const float*)d_in[8];  const float* bv1 = (const float*)d_in[9];
    const float* Wq2 = (const float*)d_in[10]; const float* bq2 = (const float*)d_in[11];
    const float* Wk2 = (const float*)d_in[12]; const float* bk2 = (const float*)d_in[13];
    const float* Wv2 = (const float*)d_in[14]; const float* bv2 = (const float*)d_in[15];

    constexpr int Bb = 16, S1 = 256, S2 = 512, VH = 1024, TH = 768;
    constexpr long M1 = (long)Bb * S1, M2 = (long)Bb * S2;
    const float scale = 0.088388347648318447f;   // 1/sqrt(128)

    // ---- workspace (fp16 elements) ----
    f16* W = (f16*)d_ws;
    f16* i1  = W;                        // [4096][1024]
    f16* i2  = i1 + M1 * VH;             // [8192][768]
    f16* w1  = i2 + M2 * TH;             // [3072][1024]
    f16* w2  = w1 + (long)3072 * VH;     // [3072][768]
    f16* q1  = w2 + (long)3072 * TH;     // [4096][1024]
    f16* k1  = q1 + M1 * 1024;
    f16* v1t = k1 + M1 * 1024;           // [16][1024][256]
    f16* q2  = v1t + M1 * 1024;          // [8192][1024]
    f16* k2  = q2 + M2 * 1024;
    f16* v2t = k2 + M2 * 1024;           // [16][1024][512]
    float* out = (float*)d_out;

    // ---- merged converts: 5120 input blocks + 1536 weight blocks ----
    cvt_all<<<dim3(6656), 256, 0, stream>>>(
        in1, M1 * VH, in2, M2 * TH, i1, i2,
        Wq1, Wk1, Wv1, Wq2, Wk2, Wv2, w1, w2);

    // ---- merged projections: 384 (s1, K=1024, long first) + 768 (s2) ----
    mm_proj<<<dim3(1152), 512, 0, stream>>>(
        i1, w1, bq1, bk1, bv1, q1, k1, v1t,
        i2, w2, bq2, bk2, bv2, q2, k2, v2t);

    // ---- merged fused attention: 256 (phase2, long) + 512 (phase1) ----
    flash<<<dim3(768), 256, 0, stream>>>(
        q2, k1, v1t, mask1, out,
        q1, k2, v2t, mask2, out + M2 * 1024, scale);
}